// Round 1
// baseline (38.070 us; speedup 1.0000x reference)
//
#include <hip/hip_runtime.h>
#include <hip/hip_bf16.h>

// EMD loss: input (N,C,S)=(32,256,4096) fp32, target (N,S) int.
// out = mean_{n,s}[ sum_c (cumsum_c(input) - [c>=target])^2 / S ]
// One thread per (n,s) column; lane-adjacent s => coalesced 256B/wave per c-step.

#define N_DIM 32
#define C_DIM 256
#define S_DIM 4096
#define S_SHIFT 12          // log2(S_DIM)
#define S_MASK  (S_DIM - 1)

__global__ __launch_bounds__(256) void emd_loss_kernel(
    const float* __restrict__ in, const int* __restrict__ tgt,
    float* __restrict__ out)
{
    const int j = blockIdx.x * blockDim.x + threadIdx.x;   // column id in [0, N*S)
    const int n = j >> S_SHIFT;
    const int s = j & S_MASK;
    const int T = tgt[j];                                  // target[n,s], row-major n*S+s == j

    const float* p = in + (size_t)n * (C_DIM * (size_t)S_DIM) + s;

    float cum = 0.0f;
    float acc = 0.0f;
    #pragma unroll 16
    for (int c = 0; c < C_DIM; ++c) {
        cum += p[(size_t)c * S_DIM];
        const float t = (c >= T) ? 1.0f : 0.0f;
        const float d = cum - t;
        acc = fmaf(d, d, acc);
    }

    // /S for the per-column norm, /(N*S) for the mean
    acc *= (1.0f / ((float)S_DIM * (float)N_DIM * (float)S_DIM));

    // wave (64-lane) shuffle reduction
    #pragma unroll
    for (int off = 32; off > 0; off >>= 1)
        acc += __shfl_down(acc, off, 64);

    __shared__ float ws[4];
    const int lane = threadIdx.x & 63;
    const int wid  = threadIdx.x >> 6;
    if (lane == 0) ws[wid] = acc;
    __syncthreads();
    if (threadIdx.x == 0) {
        atomicAdd(out, ws[0] + ws[1] + ws[2] + ws[3]);
    }
}

extern "C" void kernel_launch(void* const* d_in, const int* in_sizes, int n_in,
                              void* d_out, int out_size, void* d_ws, size_t ws_size,
                              hipStream_t stream) {
    const float* in  = (const float*)d_in[0];
    const int*   tgt = (const int*)d_in[1];
    float*       out = (float*)d_out;

    // atomic accumulation target must start at 0 every call (graph replays too)
    hipMemsetAsync(out, 0, sizeof(float), stream);

    const int columns = N_DIM * S_DIM;        // 131072
    emd_loss_kernel<<<columns / 256, 256, 0, stream>>>(in, tgt, out);
}